// Round 5
// baseline (234.238 us; speedup 1.0000x reference)
//
#include <hip/hip_runtime.h>

#define B_ 8
#define C_ 512
#define T_ 4096

typedef __attribute__((ext_vector_type(8))) __bf16 bf16x8;
typedef __attribute__((ext_vector_type(8))) _Float16 f16x8;
typedef __attribute__((ext_vector_type(8))) unsigned short u16x8;
typedef __attribute__((ext_vector_type(4))) float f32x4;

__device__ __forceinline__ unsigned short f2bf(float f) {
  unsigned int u = __float_as_uint(f);
  u += 0x7fffu + ((u >> 16) & 1u);   // RNE
  return (unsigned short)(u >> 16);
}
__device__ __forceinline__ float bf2f(unsigned short h) {
  return __uint_as_float(((unsigned int)h) << 16);
}
__device__ __forceinline__ unsigned short f2h(float f) {
  return __builtin_bit_cast(unsigned short, (_Float16)f);
}

__device__ __forceinline__ void async16(unsigned short* ldsdst, const unsigned short* gsrc) {
  __builtin_amdgcn_global_load_lds(
      (__attribute__((address_space(1))) void*)(void*)const_cast<unsigned short*>(gsrc),
      (__attribute__((address_space(3))) void*)(void*)ldsdst,
      16, 0, 0);
}

template <bool F16>
__device__ __forceinline__ f32x4 mfma16(u16x8 a, u16x8 b, f32x4 c) {
  if constexpr (F16)
    return __builtin_amdgcn_mfma_f32_16x16x32_f16(
        __builtin_bit_cast(f16x8, a), __builtin_bit_cast(f16x8, b), c, 0, 0, 0);
  else
    return __builtin_amdgcn_mfma_f32_16x16x32_bf16(
        __builtin_bit_cast(bf16x8, a), __builtin_bit_cast(bf16x8, b), c, 0, 0, 0);
}

struct GemmP {
  const unsigned short* Ah; const unsigned short* Al; long sA; int lda;
  const unsigned short* Bh; const unsigned short* Bl; long sB; int ldb;
  float* Cf; unsigned short* Ch; unsigned short* Cl; long sC; int ldc;
  int kspan; int zparts;
  const float* rowv; const float* colv; const float* bq; const float* bk;
};

enum { EPI_F32 = 0, EPI_OUT = 1, EPI_DOTS = 2, EPI_SPLIT = 3, EPI_F16 = 4 };
// SWZ: 0 = 3D grid (x,y,z); 1 = G-triangle linear grid (zparts=4), kp in low
//      bits so same-XCD blocks share a kp K-slice; 2 = out linear grid
//      (1024 blocks), bn%8 -> XCD so same-XCD blocks share the A (Mh) panel.

// NT GEMM: C[i][j] = sum_k A[i][k]*B[j][k]; optional hi/lo split (3-pass).
// Templated KC (64 or 32): KC=32 halves staging LDS -> 2x blocks/CU for the
// latency-bound kernels (R4 counters: out GEMM Occupancy 30%, all pipes idle).
// XOR-swizzled 16B chunks (conflict-free-enough ds_read_b128 + legal
// global_load_lds). 2-phase schedule: double-buffered LDS halves, stage(kt+1)
// issued BEFORE compute(kt), one barrier per K-tile. f32 epilogues staged via
// LDS, stored non-temporally.
template <int BM, int BN, int WM, int WN, int KC, bool SA, bool SB, int EPI, bool F16, int SWZ>
__global__ __launch_bounds__((BM / WM) * (BN / WN) * 64) void gemm_nt(GemmP g) {
  constexpr int NWAVE = (BM / WM) * (BN / WN);
  constexpr int NT = NWAVE * 64;
  constexpr int ASZ = BM * KC, BSZ = BN * KC;
  constexpr int SLM = KC / 8 - 1;                                  // swizzle mask
  constexpr int STAGE = (SA ? 2 : 1) * ASZ + (SB ? 2 : 1) * BSZ;  // shorts/half
  constexpr int EPAD = BN + 4;
  constexpr int EPIB = 32 * EPAD * 4;                              // bytes
  constexpr int LDSB = (STAGE * 4 > EPIB) ? STAGE * 4 : EPIB;      // 2 halves
  __shared__ alignas(16) char ldsraw[LDSB];
  unsigned short* lds = (unsigned short*)ldsraw;

  const int tid = threadIdx.x;
  const int lane = tid & 63, wid = tid >> 6;
  constexpr int WNB = BN / WN;
  const int wm = wid / WNB, wn = wid % WNB;
  constexpr int MF = WM / 16, NF = WN / 16;

  int bm, bn, z;
  if constexpr (SWZ == 1) {
    const int blk = blockIdx.x;                // 0..319
    const int r = blk & 7, q = blk >> 3;       // q 0..39
    const int idx = ((r >> 2) * 40) + q;       // 0..79 = b*10 + tri
    const int tri = idx % 10;
    const int tm = (tri >= 6) ? 3 : (tri >= 3) ? 2 : (tri >= 1) ? 1 : 0;
    bm = tm; bn = tri - (tm * (tm + 1)) / 2;
    z = (idx / 10) * 4 + (r & 3);              // b = idx/10, kp = r&3
  } else if constexpr (SWZ == 2) {
    const int blk = blockIdx.x;                // 0..1023
    const int r = blk & 7, q = blk >> 3;       // q 0..127
    bn = ((q & 3) << 3) + r;                   // 0..31
    bm = (q >> 2) & 3;                         // 0..3
    z = q >> 4;                                // batch 0..7
  } else {
    bm = blockIdx.x; bn = blockIdx.y; z = blockIdx.z;
  }
  const int b = z / g.zparts, kp = z - b * g.zparts;

  const unsigned short* Ah = g.Ah + (size_t)b * g.sA + (size_t)kp * g.kspan;
  const unsigned short* Al = SA ? (g.Al + (size_t)b * g.sA + (size_t)kp * g.kspan) : nullptr;
  const unsigned short* Bh = g.Bh + (size_t)b * g.sB + (size_t)kp * g.kspan;
  const unsigned short* Bl = SB ? (g.Bl + (size_t)b * g.sB + (size_t)kp * g.kspan) : nullptr;

  auto stage = [&](int half, int kb) {
    unsigned short* dAh = lds + half * STAGE;
    unsigned short* dAl = dAh + ASZ;
    unsigned short* dBh = dAh + (SA ? 2 : 1) * ASZ;
    unsigned short* dBl = dBh + BSZ;
#pragma unroll
    for (int r = 0; r < ASZ / (8 * NT); ++r) {
      int idx = tid + r * NT;
      int row = idx >> (KC == 64 ? 3 : 2), sl = idx & (KC == 64 ? 7 : 3);
      int kc = (sl ^ (row & SLM)) << 3;                // XOR swizzle
      size_t goff = (size_t)(bm * BM + row) * g.lda + kb + kc;
      async16(&dAh[idx << 3], Ah + goff);
      if constexpr (SA) async16(&dAl[idx << 3], Al + goff);
    }
#pragma unroll
    for (int r = 0; r < BSZ / (8 * NT); ++r) {
      int idx = tid + r * NT;
      int row = idx >> (KC == 64 ? 3 : 2), sl = idx & (KC == 64 ? 7 : 3);
      int kc = (sl ^ (row & SLM)) << 3;
      size_t goff = (size_t)(bn * BN + row) * g.ldb + kb + kc;
      async16(&dBh[idx << 3], Bh + goff);
      if constexpr (SB) async16(&dBl[idx << 3], Bl + goff);
    }
  };

  f32x4 acc[MF][NF] = {};

  const int kIters = g.kspan / KC;
  stage(0, 0);
  __syncthreads();
  for (int kt = 0; kt < kIters; ++kt) {
    if (kt + 1 < kIters) stage((kt + 1) & 1, (kt + 1) * KC);  // prefetch next

    const unsigned short* cAh = lds + (kt & 1) * STAGE;
    const unsigned short* cAl = cAh + ASZ;
    const unsigned short* cBh = cAh + (SA ? 2 : 1) * ASZ;
    const unsigned short* cBl = cBh + BSZ;

    const int rsel = lane & 15, kq = lane >> 4;
#pragma unroll
    for (int ks = 0; ks < KC; ks += 32) {
      const int chunk = (ks >> 3) + kq;
      u16x8 afh[MF], afl[MF], bfh[NF], bfl[NF];
#pragma unroll
      for (int fm = 0; fm < MF; ++fm) {
        int row = wm * WM + fm * 16 + rsel;
        int ro = row * KC + ((chunk ^ (row & SLM)) << 3);
        afh[fm] = *(const u16x8*)&cAh[ro];
        if constexpr (SA) afl[fm] = *(const u16x8*)&cAl[ro];
      }
#pragma unroll
      for (int fn = 0; fn < NF; ++fn) {
        int row = wn * WN + fn * 16 + rsel;
        int ro = row * KC + ((chunk ^ (row & SLM)) << 3);
        bfh[fn] = *(const u16x8*)&cBh[ro];
        if constexpr (SB) bfl[fn] = *(const u16x8*)&cBl[ro];
      }
#pragma unroll
      for (int fm = 0; fm < MF; ++fm)
#pragma unroll
        for (int fn = 0; fn < NF; ++fn) {
          acc[fm][fn] = mfma16<F16>(afh[fm], bfh[fn], acc[fm][fn]);
          if constexpr (SB) acc[fm][fn] = mfma16<F16>(afh[fm], bfl[fn], acc[fm][fn]);
          if constexpr (SA) acc[fm][fn] = mfma16<F16>(afl[fm], bfh[fn], acc[fm][fn]);
        }
    }
    __syncthreads();  // drains vmcnt (stage kt+1 done) + LDS reads of cur done
  }

  if constexpr (EPI == EPI_SPLIT || EPI == EPI_F16) {
#pragma unroll
    for (int fm = 0; fm < MF; ++fm)
#pragma unroll
      for (int fn = 0; fn < NF; ++fn)
#pragma unroll
        for (int r = 0; r < 4; ++r) {
          int i = bm * BM + wm * WM + fm * 16 + ((lane >> 4) << 2) + r;
          int j = bn * BN + wn * WN + fn * 16 + (lane & 15);
          float v = acc[fm][fn][r];
          size_t co = (size_t)z * g.sC + (size_t)i * g.ldc + j;
          if constexpr (EPI == EPI_SPLIT) {
            unsigned short h = f2bf(v);
            g.Ch[co] = h;
            g.Cl[co] = f2bf(v - bf2f(h));
          } else {
            g.Ch[co] = f2h(v);
          }
        }
  } else {
    // Chunked LDS epilogue: 32 rows x BN f32 per chunk, coalesced nt stores.
    float* eb = (float*)ldsraw;
#pragma unroll
    for (int ck = 0; ck < BM / 32; ++ck) {
      if (wm == (ck * 32) / WM) {
        const int fm0 = ((ck * 32) % WM) / 16;
#pragma unroll
        for (int fi = 0; fi < 2; ++fi) {
          int fm = fm0 + fi;
#pragma unroll
          for (int fn = 0; fn < NF; ++fn)
#pragma unroll
            for (int r = 0; r < 4; ++r) {
              int lrow = fi * 16 + ((lane >> 4) << 2) + r;
              int col = wn * WN + fn * 16 + (lane & 15);
              eb[lrow * EPAD + col] = acc[fm][fn][r];
            }
        }
      }
      __syncthreads();
#pragma unroll
      for (int it = 0; it < (32 * BN / 4) / NT; ++it) {
        int idx = it * NT + tid;
        int row = idx / (BN / 4), c4 = (idx % (BN / 4)) * 4;
        f32x4 v = *(f32x4*)&eb[row * EPAD + c4];
        int grow = bm * BM + ck * 32 + row;
        int j = bn * BN + c4;
        if constexpr (EPI == EPI_OUT) v = v + g.rowv[b * C_ + grow];
        if constexpr (EPI == EPI_DOTS) {
          f32x4 bkv = *(const f32x4*)&g.bk[j];
          f32x4 ksv = *(const f32x4*)&g.colv[b * C_ + j];
          float qsi = g.rowv[b * C_ + grow], bqi = g.bq[grow];
          v = 0.125f * (v + qsi * bkv + bqi * (ksv + 4096.f * bkv));
        }
        __builtin_nontemporal_store(
            v, (f32x4*)&g.Cf[(size_t)z * g.sC + (size_t)grow * g.ldc + j]);
      }
      __syncthreads();
    }
  }
}

// Fused prep: x blocks 64c x 256t, software-pipelined sub-tiles (loads for
// sub-tile st+1 issued before st's transpose barrier) -> Xh + XhT; fused
// per-row partial sums (fp16-rounded values) atomicAdd'ed into S.
// Weight blocks: Wq/Wk -> bf16 hi/lo, Wv -> transposed fp16.
#define NXB2 1024
#define PAD 66
__global__ __launch_bounds__(256) void prep_fused(
    const float* __restrict__ x, const float* __restrict__ Wq,
    const float* __restrict__ Wk, const float* __restrict__ Wv,
    unsigned short* __restrict__ Xh, unsigned short* __restrict__ XhT,
    unsigned short* Wqh, unsigned short* Wql,
    unsigned short* Wkh, unsigned short* Wkl, unsigned short* WvT,
    float* __restrict__ S) {
  __shared__ unsigned short tile[64 * PAD];
  const int tid = threadIdx.x;
  if (blockIdx.x < NXB2) {
    const int tl = blockIdx.x;
    const int tb = tl & 15, c0 = ((tl >> 4) & 7) << 6, b = tl >> 7;
    const int t0 = tb << 8;
    const float* xin = x + ((size_t)(b * C_ + c0)) * T_ + t0;
    unsigned short* xo = Xh + ((size_t)(b * C_ + c0)) * T_ + t0;
    const int row16 = tid >> 4, c4 = (tid & 15) << 2;
    float rs[4] = {};
    float4 v[4];
#pragma unroll
    for (int r = 0; r < 4; ++r)
      v[r] = *(const float4*)&xin[(size_t)(row16 + r * 16) * T_ + c4];
    for (int st = 0; st < 4; ++st) {
      if (st) __syncthreads();
#pragma unroll
      for (int r = 0; r < 4; ++r) {
        int row = row16 + r * 16;
        _Float16 q0 = (_Float16)v[r].x, q1 = (_Float16)v[r].y,
                 q2 = (_Float16)v[r].z, q3 = (_Float16)v[r].w;
        unsigned short h0 = __builtin_bit_cast(unsigned short, q0),
                       h1 = __builtin_bit_cast(unsigned short, q1),
                       h2 = __builtin_bit_cast(unsigned short, q2),
                       h3 = __builtin_bit_cast(unsigned short, q3);
        rs[r] += (float)q0 + (float)q1 + (float)q2 + (float)q3;
        ushort4 hv; hv.x = h0; hv.y = h1; hv.z = h2; hv.w = h3;
        *(ushort4*)&xo[(size_t)row * T_ + st * 64 + c4] = hv;
        unsigned int lo = (unsigned int)h0 | ((unsigned int)h1 << 16);
        unsigned int hi = (unsigned int)h2 | ((unsigned int)h3 << 16);
        ((unsigned int*)&tile[row * PAD + c4])[0] = lo;
        ((unsigned int*)&tile[row * PAD + c4])[1] = hi;
      }
      float4 nv[4];
      if (st < 3) {
#pragma unroll
        for (int r = 0; r < 4; ++r)
          nv[r] = *(const float4*)&xin[(size_t)(row16 + r * 16) * T_ + (st + 1) * 64 + c4];
      }
      __syncthreads();
#pragma unroll
      for (int r = 0; r < 2; ++r) {
        int idx = tid + r * 256;
        int trow = idx >> 3, cc = (idx & 7) << 3;
        unsigned short vals[8];
#pragma unroll
        for (int j = 0; j < 8; ++j) vals[j] = tile[(cc + j) * PAD + trow];
        *(uint4*)&XhT[((size_t)b * T_ + t0 + st * 64 + trow) * C_ + c0 + cc] =
            *(uint4*)vals;
      }
#pragma unroll
      for (int r = 0; r < 4; ++r) v[r] = nv[r];
    }
    // Fused row-sum: reduce across the 16 lanes of each row-group, one
    // atomicAdd per (row, t-block). 16 atomics/entry total -> no contention.
#pragma unroll
    for (int rr = 0; rr < 4; ++rr) {
      float s = rs[rr];
      s += __shfl_down(s, 8, 16);
      s += __shfl_down(s, 4, 16);
      s += __shfl_down(s, 2, 16);
      s += __shfl_down(s, 1, 16);
      if ((tid & 15) == 0) atomicAdd(&S[(b << 9) + c0 + row16 + rr * 16], s);
    }
  } else {
    int i = (blockIdx.x - NXB2) * 256 + tid;  // 0..C*C-1
    float q = Wq[i]; unsigned short qh = f2bf(q); Wqh[i] = qh; Wql[i] = f2bf(q - bf2f(qh));
    float k = Wk[i]; unsigned short kh = f2bf(k); Wkh[i] = kh; Wkl[i] = f2bf(k - bf2f(kh));
    float v = Wv[i]; int d = i >> 9, e = i & 511;
    WvT[(e << 9) + d] = f2h(v);
  }
}

// G combine: sum 4 splitK partials from the lower-triangle source tile
// (transposing via LDS for mirrored upper tiles) -> bf16 hi/lo full square.
__global__ __launch_bounds__(256) void combine_g(const float* __restrict__ gp,
                                                 unsigned short* __restrict__ gh,
                                                 unsigned short* __restrict__ gl) {
  __shared__ float tile[64 * 65];
  const int blk = blockIdx.x;             // b = blk&7; q = blk>>3 -> 64x64 tiles
  const int b = blk & 7, q = blk >> 3;
  const int tr = q >> 3, tc = q & 7;
  const bool mirror = (tr >> 1) < (tc >> 1);      // containing 128-tile is upper
  const int sr = mirror ? tc : tr, sc = mirror ? tr : tc;
  const float* src = gp + ((size_t)b << 20) + (size_t)(sr << 6) * 512 + (sc << 6);
  const int row = threadIdx.x >> 4, c4 = (threadIdx.x & 15) << 2;
  float vals[4][4];
#pragma unroll
  for (int rr = 0; rr < 4; ++rr) {
    const int r = row + rr * 16;
    f32x4 v = {};
#pragma unroll
    for (int p = 0; p < 4; ++p)
      v += __builtin_nontemporal_load(
          (const f32x4*)&src[((size_t)p << 18) + (size_t)r * 512 + c4]);
    if (mirror) {
#pragma unroll
      for (int k = 0; k < 4; ++k) tile[r * 65 + c4 + k] = v[k];
    } else {
#pragma unroll
      for (int k = 0; k < 4; ++k) vals[rr][k] = v[k];
    }
  }
  if (mirror) {
    __syncthreads();
#pragma unroll
    for (int rr = 0; rr < 4; ++rr) {
      const int r = row + rr * 16;
#pragma unroll
      for (int k = 0; k < 4; ++k) vals[rr][k] = tile[(c4 + k) * 65 + r];
    }
  }
  unsigned short* ghp = gh + ((size_t)b << 18) + (size_t)(tr << 6) * 512 + (tc << 6);
  unsigned short* glp = gl + ((size_t)b << 18) + (size_t)(tr << 6) * 512 + (tc << 6);
#pragma unroll
  for (int rr = 0; rr < 4; ++rr) {
    const int r = row + rr * 16;
    ushort4 h, l;
    h.x = f2bf(vals[rr][0]); l.x = f2bf(vals[rr][0] - bf2f(h.x));
    h.y = f2bf(vals[rr][1]); l.y = f2bf(vals[rr][1] - bf2f(h.y));
    h.z = f2bf(vals[rr][2]); l.z = f2bf(vals[rr][2] - bf2f(h.z));
    h.w = f2bf(vals[rr][3]); l.w = f2bf(vals[rr][3] - bf2f(h.w));
    *(ushort4*)&ghp[(size_t)r * 512 + c4] = h;
    *(ushort4*)&glp[(size_t)r * 512 + c4] = l;
  }
}

// qs[b,i] = sum_c Wq[i,c] s[b,c];  ks[b,i] = sum_c Wk[i,c] s[b,c]
__global__ __launch_bounds__(256) void qs_ks(const float* __restrict__ Wq, const float* __restrict__ Wk,
                                             const float* __restrict__ s, float* __restrict__ qs,
                                             float* __restrict__ ks) {
  int lane = threadIdx.x & 63, wid = threadIdx.x >> 6;
  int gi = blockIdx.x * 4 + wid;
  int b = gi >> 9, i = gi & 511;
  const float* sv = s + (b << 9);
  const float* wqr = Wq + (size_t)i * C_;
  const float* wkr = Wk + (size_t)i * C_;
  float aq = 0.f, ak = 0.f;
#pragma unroll
  for (int c = lane; c < C_; c += 64) {
    float sc = sv[c];
    aq += wqr[c] * sc;
    ak += wkr[c] * sc;
  }
#pragma unroll
  for (int o = 32; o > 0; o >>= 1) { aq += __shfl_down(aq, o); ak += __shfl_down(ak, o); }
  if (lane == 0) { qs[gi] = aq; ks[gi] = ak; }
}

// rowwise softmax over 512 logits; attn fp16; ab[b,c] = sum_d attn*bv[d]
__global__ __launch_bounds__(256) void softmax_rows(const float* __restrict__ logits,
                                                    const float* __restrict__ bv,
                                                    unsigned short* __restrict__ attn,
                                                    float* __restrict__ ab) {
  const int row = blockIdx.x;
  const int tid = threadIdx.x, lane = tid & 63, wid = tid >> 6;
  const float* L = logits + (size_t)row * C_;
  float v0 = __builtin_nontemporal_load(&L[tid]);
  float v1 = __builtin_nontemporal_load(&L[tid + 256]);
  __shared__ float red[4];
  float m = fmaxf(v0, v1);
#pragma unroll
  for (int o = 32; o > 0; o >>= 1) m = fmaxf(m, __shfl_down(m, o));
  if (lane == 0) red[wid] = m;
  __syncthreads();
  m = fmaxf(fmaxf(red[0], red[1]), fmaxf(red[2], red[3]));
  __syncthreads();
  float e0 = __expf(v0 - m), e1 = __expf(v1 - m);
  float sum = e0 + e1;
#pragma unroll
  for (int o = 32; o > 0; o >>= 1) sum += __shfl_down(sum, o);
  if (lane == 0) red[wid] = sum;
  __syncthreads();
  sum = red[0] + red[1] + red[2] + red[3];
  float inv = 1.f / sum;
  float a0 = e0 * inv, a1 = e1 * inv;
  unsigned short* ar = attn + (size_t)row * C_;
  ar[tid] = f2h(a0);
  ar[tid + 256] = f2h(a1);
  float abv = a0 * bv[tid] + a1 * bv[tid + 256];
  __syncthreads();
#pragma unroll
  for (int o = 32; o > 0; o >>= 1) abv += __shfl_down(abv, o);
  if (lane == 0) red[wid] = abv;
  __syncthreads();
  if (tid == 0) ab[row] = red[0] + red[1] + red[2] + red[3];
}

extern "C" void kernel_launch(void* const* d_in, const int* in_sizes, int n_in,
                              void* d_out, int out_size, void* d_ws, size_t ws_size,
                              hipStream_t stream) {
  const float* x  = (const float*)d_in[0];
  const float* Wq = (const float*)d_in[1];
  const float* bq = (const float*)d_in[2];
  const float* Wk = (const float*)d_in[3];
  const float* bk = (const float*)d_in[4];
  const float* Wv = (const float*)d_in[5];
  const float* bv = (const float*)d_in[6];
  float* out = (float*)d_out;

  char* ws = (char*)d_ws;
  size_t off = 0;
  auto alloc = [&](size_t bytes) {
    char* p = ws + off;
    off += (bytes + 255) & ~(size_t)255;
    return p;
  };
  const size_t XSZ = (size_t)B_ * C_ * T_;
  const size_t GSZ = (size_t)B_ * C_ * C_;   // 2^21

  unsigned short* Xh  = (unsigned short*)alloc(XSZ * 2);
  unsigned short* XhT = (unsigned short*)alloc(XSZ * 2);
  float* Gpart = (float*)alloc((size_t)4 * GSZ * 4);   // 33.5 MB (4 splitK parts)
  unsigned short* Gh = (unsigned short*)alloc(GSZ * 2);
  unsigned short* Gl = (unsigned short*)alloc(GSZ * 2);
  unsigned short* Ph = (unsigned short*)alloc(GSZ * 2);
  unsigned short* Pl = (unsigned short*)alloc(GSZ * 2);
  float* Logits = (float*)alloc(GSZ * 4);
  unsigned short* Attn = (unsigned short*)alloc(GSZ * 2);
  unsigned short* Mh = (unsigned short*)alloc(GSZ * 2);
  unsigned short* Wqh = (unsigned short*)alloc((size_t)C_ * C_ * 2);
  unsigned short* Wql = (unsigned short*)alloc((size_t)C_ * C_ * 2);
  unsigned short* Wkh = (unsigned short*)alloc((size_t)C_ * C_ * 2);
  unsigned short* Wkl = (unsigned short*)alloc((size_t)C_ * C_ * 2);
  unsigned short* WvT = (unsigned short*)alloc((size_t)C_ * C_ * 2);
  float* S  = (float*)alloc((size_t)B_ * C_ * 4);
  float* Qs = (float*)alloc((size_t)B_ * C_ * 4);
  float* Ks = (float*)alloc((size_t)B_ * C_ * 4);
  float* Ab = (float*)alloc((size_t)B_ * C_ * 4);

  hipMemsetAsync(S, 0, (size_t)B_ * C_ * 4, stream);
  prep_fused<<<NXB2 + C_ * C_ / 256, 256, 0, stream>>>(x, Wq, Wk, Wv, Xh, XhT,
                                                       Wqh, Wql, Wkh, Wkl, WvT, S);
  qs_ks<<<B_ * C_ / 4, 256, 0, stream>>>(Wq, Wk, S, Qs, Ks);

  {  // G = X X^T, fp16, lower-triangle 128-tiles, splitK=4, XCD-swizzled
    GemmP p = {};
    p.Ah = Xh; p.sA = (long)C_ * T_; p.lda = T_;
    p.Bh = Xh; p.sB = (long)C_ * T_; p.ldb = T_;
    p.Cf = Gpart; p.sC = (long)C_ * C_; p.ldc = C_;
    p.kspan = T_ / 4; p.zparts = 4;
    gemm_nt<128, 128, 32, 64, 64, false, false, EPI_F32, true, 1>
        <<<320, 512, 0, stream>>>(p);
  }
  combine_g<<<B_ * 64, 256, 0, stream>>>(Gpart, Gh, Gl);

  {  // P = Wq G (bf16 hi/lo 3-pass), direct split output, KC=32 (5 blk/CU)
    GemmP p = {};
    p.Ah = Wqh; p.Al = Wql; p.sA = 0; p.lda = C_;
    p.Bh = Gh; p.Bl = Gl; p.sB = (long)C_ * C_; p.ldb = C_;
    p.Ch = Ph; p.Cl = Pl; p.sC = (long)C_ * C_; p.ldc = C_;
    p.kspan = C_; p.zparts = 1;
    gemm_nt<64, 64, 32, 32, 32, true, true, EPI_SPLIT, false, 0>
        <<<dim3(8, 8, 8), 256, 0, stream>>>(p);
  }
  {  // logits = 0.125*(P Wk^T + rank-1 bias terms), fp32 nt stores, KC=32
    GemmP p = {};
    p.Ah = Ph; p.Al = Pl; p.sA = (long)C_ * C_; p.lda = C_;
    p.Bh = Wkh; p.Bl = Wkl; p.sB = 0; p.ldb = C_;
    p.Cf = Logits; p.sC = (long)C_ * C_; p.ldc = C_;
    p.kspan = C_; p.zparts = 1;
    p.rowv = Qs; p.colv = Ks; p.bq = bq; p.bk = bk;
    gemm_nt<64, 64, 32, 32, 32, true, true, EPI_DOTS, false, 0>
        <<<dim3(8, 8, 8), 256, 0, stream>>>(p);
  }
  softmax_rows<<<B_ * C_, 256, 0, stream>>>(Logits, bv, Attn, Ab);
  {  // M = attn Wv (fp16, NT with WvT), direct fp16 output, KC=32 (8 blk/CU)
    GemmP p = {};
    p.Ah = Attn; p.sA = (long)C_ * C_; p.lda = C_;
    p.Bh = WvT; p.sB = 0; p.ldb = C_;
    p.Ch = Mh; p.sC = (long)C_ * C_; p.ldc = C_;
    p.kspan = C_; p.zparts = 1;
    gemm_nt<64, 64, 32, 32, 32, false, false, EPI_F16, true, 0>
        <<<dim3(8, 8, 8), 256, 0, stream>>>(p);
  }
  {  // out = M X + ab (fp16, NT with XhT), 128x128 8-wave dbuf, KC=32
     // (32 KB LDS -> 4 blk/CU = 100% thread occupancy), XCD-swizzled
    GemmP p = {};
    p.Ah = Mh; p.sA = (long)C_ * C_; p.lda = C_;
    p.Bh = XhT; p.sB = (long)C_ * T_; p.ldb = C_;
    p.Cf = out; p.sC = (long)C_ * T_; p.ldc = T_;
    p.kspan = C_; p.zparts = 1;
    p.rowv = Ab;
    gemm_nt<128, 128, 32, 64, 32, false, false, EPI_OUT, true, 2>
        <<<1024, 512, 0, stream>>>(p);
  }
  (void)in_sizes; (void)n_in; (void)out_size; (void)ws_size;
}

// Round 6
// 227.962 us; speedup vs baseline: 1.0275x; 1.0275x over previous
//
#include <hip/hip_runtime.h>

#define B_ 8
#define C_ 512
#define T_ 4096

typedef __attribute__((ext_vector_type(8))) __bf16 bf16x8;
typedef __attribute__((ext_vector_type(8))) _Float16 f16x8;
typedef __attribute__((ext_vector_type(8))) unsigned short u16x8;
typedef __attribute__((ext_vector_type(4))) float f32x4;

__device__ __forceinline__ unsigned short f2bf(float f) {
  unsigned int u = __float_as_uint(f);
  u += 0x7fffu + ((u >> 16) & 1u);   // RNE
  return (unsigned short)(u >> 16);
}
__device__ __forceinline__ float bf2f(unsigned short h) {
  return __uint_as_float(((unsigned int)h) << 16);
}
__device__ __forceinline__ unsigned short f2h(float f) {
  return __builtin_bit_cast(unsigned short, (_Float16)f);
}

__device__ __forceinline__ void async16(unsigned short* ldsdst, const unsigned short* gsrc) {
  __builtin_amdgcn_global_load_lds(
      (__attribute__((address_space(1))) void*)(void*)const_cast<unsigned short*>(gsrc),
      (__attribute__((address_space(3))) void*)(void*)ldsdst,
      16, 0, 0);
}

template <bool F16>
__device__ __forceinline__ f32x4 mfma16(u16x8 a, u16x8 b, f32x4 c) {
  if constexpr (F16)
    return __builtin_amdgcn_mfma_f32_16x16x32_f16(
        __builtin_bit_cast(f16x8, a), __builtin_bit_cast(f16x8, b), c, 0, 0, 0);
  else
    return __builtin_amdgcn_mfma_f32_16x16x32_bf16(
        __builtin_bit_cast(bf16x8, a), __builtin_bit_cast(bf16x8, b), c, 0, 0, 0);
}

struct GemmP {
  const unsigned short* Ah; const unsigned short* Al; long sA; int lda;
  const unsigned short* Bh; const unsigned short* Bl; long sB; int ldb;
  float* Cf; unsigned short* Ch; unsigned short* Cl; long sC; int ldc;
  int kspan; int zparts;
  const float* rowv; const float* colv; const float* bq; const float* bk;
};

enum { EPI_F32 = 0, EPI_OUT = 1, EPI_DOTS = 2, EPI_SPLIT = 3, EPI_F16 = 4 };
// SWZ: 0 = 3D grid (x,y,z); 1 = G-triangle linear grid (zparts=4), kp in low
//      bits so same-XCD blocks share a kp K-slice; 2 = out linear grid
//      (1024 blocks), bn%8 -> XCD so same-XCD blocks share the A (Mh) panel.

// NT GEMM: C[i][j] = sum_k A[i][k]*B[j][k]; optional hi/lo split (3-pass).
// KC policy (R4/R5 A/B): KC=32 ONLY where occupancy is LDS-capped with
// 512-thread blocks (out GEMM: 2->4 blk/CU, confirmed -4us+). For K=512
// 256-thread GEMMs (P/logits/M) KC=32 doubled barriers and REGRESSED ~8us
// -> they stay at KC=64. KC does not change MFMA accumulation order
// (bit-identical numerics).
// XOR-swizzled 16B chunks (conflict-free ds_read_b128 + legal
// global_load_lds). 2-phase schedule: double-buffered LDS halves, stage(kt+1)
// issued BEFORE compute(kt), one barrier per K-tile. f32 epilogues staged via
// LDS, stored non-temporally.
template <int BM, int BN, int WM, int WN, int KC, bool SA, bool SB, int EPI, bool F16, int SWZ>
__global__ __launch_bounds__((BM / WM) * (BN / WN) * 64) void gemm_nt(GemmP g) {
  constexpr int NWAVE = (BM / WM) * (BN / WN);
  constexpr int NT = NWAVE * 64;
  constexpr int ASZ = BM * KC, BSZ = BN * KC;
  constexpr int SLM = KC / 8 - 1;                                  // swizzle mask
  constexpr int STAGE = (SA ? 2 : 1) * ASZ + (SB ? 2 : 1) * BSZ;  // shorts/half
  constexpr int EPAD = BN + 4;
  constexpr int EPIB = 32 * EPAD * 4;                              // bytes
  constexpr int LDSB = (STAGE * 4 > EPIB) ? STAGE * 4 : EPIB;      // 2 halves
  __shared__ alignas(16) char ldsraw[LDSB];
  unsigned short* lds = (unsigned short*)ldsraw;

  const int tid = threadIdx.x;
  const int lane = tid & 63, wid = tid >> 6;
  constexpr int WNB = BN / WN;
  const int wm = wid / WNB, wn = wid % WNB;
  constexpr int MF = WM / 16, NF = WN / 16;

  int bm, bn, z;
  if constexpr (SWZ == 1) {
    const int blk = blockIdx.x;                // 0..319
    const int r = blk & 7, q = blk >> 3;       // q 0..39
    const int idx = ((r >> 2) * 40) + q;       // 0..79 = b*10 + tri
    const int tri = idx % 10;
    const int tm = (tri >= 6) ? 3 : (tri >= 3) ? 2 : (tri >= 1) ? 1 : 0;
    bm = tm; bn = tri - (tm * (tm + 1)) / 2;
    z = (idx / 10) * 4 + (r & 3);              // b = idx/10, kp = r&3
  } else if constexpr (SWZ == 2) {
    const int blk = blockIdx.x;                // 0..1023
    const int r = blk & 7, q = blk >> 3;       // q 0..127
    bn = ((q & 3) << 3) + r;                   // 0..31
    bm = (q >> 2) & 3;                         // 0..3
    z = q >> 4;                                // batch 0..7
  } else {
    bm = blockIdx.x; bn = blockIdx.y; z = blockIdx.z;
  }
  const int b = z / g.zparts, kp = z - b * g.zparts;

  const unsigned short* Ah = g.Ah + (size_t)b * g.sA + (size_t)kp * g.kspan;
  const unsigned short* Al = SA ? (g.Al + (size_t)b * g.sA + (size_t)kp * g.kspan) : nullptr;
  const unsigned short* Bh = g.Bh + (size_t)b * g.sB + (size_t)kp * g.kspan;
  const unsigned short* Bl = SB ? (g.Bl + (size_t)b * g.sB + (size_t)kp * g.kspan) : nullptr;

  auto stage = [&](int half, int kb) {
    unsigned short* dAh = lds + half * STAGE;
    unsigned short* dAl = dAh + ASZ;
    unsigned short* dBh = dAh + (SA ? 2 : 1) * ASZ;
    unsigned short* dBl = dBh + BSZ;
#pragma unroll
    for (int r = 0; r < ASZ / (8 * NT); ++r) {
      int idx = tid + r * NT;
      int row = idx >> (KC == 64 ? 3 : 2), sl = idx & (KC == 64 ? 7 : 3);
      int kc = (sl ^ (row & SLM)) << 3;                // XOR swizzle
      size_t goff = (size_t)(bm * BM + row) * g.lda + kb + kc;
      async16(&dAh[idx << 3], Ah + goff);
      if constexpr (SA) async16(&dAl[idx << 3], Al + goff);
    }
#pragma unroll
    for (int r = 0; r < BSZ / (8 * NT); ++r) {
      int idx = tid + r * NT;
      int row = idx >> (KC == 64 ? 3 : 2), sl = idx & (KC == 64 ? 7 : 3);
      int kc = (sl ^ (row & SLM)) << 3;
      size_t goff = (size_t)(bn * BN + row) * g.ldb + kb + kc;
      async16(&dBh[idx << 3], Bh + goff);
      if constexpr (SB) async16(&dBl[idx << 3], Bl + goff);
    }
  };

  f32x4 acc[MF][NF] = {};

  const int kIters = g.kspan / KC;
  stage(0, 0);
  __syncthreads();
  for (int kt = 0; kt < kIters; ++kt) {
    if (kt + 1 < kIters) stage((kt + 1) & 1, (kt + 1) * KC);  // prefetch next

    const unsigned short* cAh = lds + (kt & 1) * STAGE;
    const unsigned short* cAl = cAh + ASZ;
    const unsigned short* cBh = cAh + (SA ? 2 : 1) * ASZ;
    const unsigned short* cBl = cBh + BSZ;

    const int rsel = lane & 15, kq = lane >> 4;
#pragma unroll
    for (int ks = 0; ks < KC; ks += 32) {
      const int chunk = (ks >> 3) + kq;
      u16x8 afh[MF], afl[MF], bfh[NF], bfl[NF];
#pragma unroll
      for (int fm = 0; fm < MF; ++fm) {
        int row = wm * WM + fm * 16 + rsel;
        int ro = row * KC + ((chunk ^ (row & SLM)) << 3);
        afh[fm] = *(const u16x8*)&cAh[ro];
        if constexpr (SA) afl[fm] = *(const u16x8*)&cAl[ro];
      }
#pragma unroll
      for (int fn = 0; fn < NF; ++fn) {
        int row = wn * WN + fn * 16 + rsel;
        int ro = row * KC + ((chunk ^ (row & SLM)) << 3);
        bfh[fn] = *(const u16x8*)&cBh[ro];
        if constexpr (SB) bfl[fn] = *(const u16x8*)&cBl[ro];
      }
#pragma unroll
      for (int fm = 0; fm < MF; ++fm)
#pragma unroll
        for (int fn = 0; fn < NF; ++fn) {
          acc[fm][fn] = mfma16<F16>(afh[fm], bfh[fn], acc[fm][fn]);
          if constexpr (SB) acc[fm][fn] = mfma16<F16>(afh[fm], bfl[fn], acc[fm][fn]);
          if constexpr (SA) acc[fm][fn] = mfma16<F16>(afl[fm], bfh[fn], acc[fm][fn]);
        }
    }
    __syncthreads();  // drains vmcnt (stage kt+1 done) + LDS reads of cur done
  }

  if constexpr (EPI == EPI_SPLIT || EPI == EPI_F16) {
#pragma unroll
    for (int fm = 0; fm < MF; ++fm)
#pragma unroll
      for (int fn = 0; fn < NF; ++fn)
#pragma unroll
        for (int r = 0; r < 4; ++r) {
          int i = bm * BM + wm * WM + fm * 16 + ((lane >> 4) << 2) + r;
          int j = bn * BN + wn * WN + fn * 16 + (lane & 15);
          float v = acc[fm][fn][r];
          size_t co = (size_t)z * g.sC + (size_t)i * g.ldc + j;
          if constexpr (EPI == EPI_SPLIT) {
            unsigned short h = f2bf(v);
            g.Ch[co] = h;
            g.Cl[co] = f2bf(v - bf2f(h));
          } else {
            g.Ch[co] = f2h(v);
          }
        }
  } else {
    // Chunked LDS epilogue: 32 rows x BN f32 per chunk, coalesced nt stores.
    float* eb = (float*)ldsraw;
#pragma unroll
    for (int ck = 0; ck < BM / 32; ++ck) {
      if (wm == (ck * 32) / WM) {
        const int fm0 = ((ck * 32) % WM) / 16;
#pragma unroll
        for (int fi = 0; fi < 2; ++fi) {
          int fm = fm0 + fi;
#pragma unroll
          for (int fn = 0; fn < NF; ++fn)
#pragma unroll
            for (int r = 0; r < 4; ++r) {
              int lrow = fi * 16 + ((lane >> 4) << 2) + r;
              int col = wn * WN + fn * 16 + (lane & 15);
              eb[lrow * EPAD + col] = acc[fm][fn][r];
            }
        }
      }
      __syncthreads();
#pragma unroll
      for (int it = 0; it < (32 * BN / 4) / NT; ++it) {
        int idx = it * NT + tid;
        int row = idx / (BN / 4), c4 = (idx % (BN / 4)) * 4;
        f32x4 v = *(f32x4*)&eb[row * EPAD + c4];
        int grow = bm * BM + ck * 32 + row;
        int j = bn * BN + c4;
        if constexpr (EPI == EPI_OUT) v = v + g.rowv[b * C_ + grow];
        if constexpr (EPI == EPI_DOTS) {
          f32x4 bkv = *(const f32x4*)&g.bk[j];
          f32x4 ksv = *(const f32x4*)&g.colv[b * C_ + j];
          float qsi = g.rowv[b * C_ + grow], bqi = g.bq[grow];
          v = 0.125f * (v + qsi * bkv + bqi * (ksv + 4096.f * bkv));
        }
        __builtin_nontemporal_store(
            v, (f32x4*)&g.Cf[(size_t)z * g.sC + (size_t)grow * g.ldc + j]);
      }
      __syncthreads();
    }
  }
}

// Fused prep: x blocks 64c x 256t, software-pipelined sub-tiles (loads for
// sub-tile st+1 issued before st's transpose barrier) -> Xh + XhT; fused
// per-row partial sums (fp16-rounded values) atomicAdd'ed into S.
// Weight blocks: Wq/Wk -> bf16 hi/lo, Wv -> transposed fp16.
#define NXB2 1024
#define PAD 66
__global__ __launch_bounds__(256) void prep_fused(
    const float* __restrict__ x, const float* __restrict__ Wq,
    const float* __restrict__ Wk, const float* __restrict__ Wv,
    unsigned short* __restrict__ Xh, unsigned short* __restrict__ XhT,
    unsigned short* Wqh, unsigned short* Wql,
    unsigned short* Wkh, unsigned short* Wkl, unsigned short* WvT,
    float* __restrict__ S) {
  __shared__ unsigned short tile[64 * PAD];
  const int tid = threadIdx.x;
  if (blockIdx.x < NXB2) {
    const int tl = blockIdx.x;
    const int tb = tl & 15, c0 = ((tl >> 4) & 7) << 6, b = tl >> 7;
    const int t0 = tb << 8;
    const float* xin = x + ((size_t)(b * C_ + c0)) * T_ + t0;
    unsigned short* xo = Xh + ((size_t)(b * C_ + c0)) * T_ + t0;
    const int row16 = tid >> 4, c4 = (tid & 15) << 2;
    float rs[4] = {};
    float4 v[4];
#pragma unroll
    for (int r = 0; r < 4; ++r)
      v[r] = *(const float4*)&xin[(size_t)(row16 + r * 16) * T_ + c4];
    for (int st = 0; st < 4; ++st) {
      if (st) __syncthreads();
#pragma unroll
      for (int r = 0; r < 4; ++r) {
        int row = row16 + r * 16;
        _Float16 q0 = (_Float16)v[r].x, q1 = (_Float16)v[r].y,
                 q2 = (_Float16)v[r].z, q3 = (_Float16)v[r].w;
        unsigned short h0 = __builtin_bit_cast(unsigned short, q0),
                       h1 = __builtin_bit_cast(unsigned short, q1),
                       h2 = __builtin_bit_cast(unsigned short, q2),
                       h3 = __builtin_bit_cast(unsigned short, q3);
        rs[r] += (float)q0 + (float)q1 + (float)q2 + (float)q3;
        ushort4 hv; hv.x = h0; hv.y = h1; hv.z = h2; hv.w = h3;
        *(ushort4*)&xo[(size_t)row * T_ + st * 64 + c4] = hv;
        unsigned int lo = (unsigned int)h0 | ((unsigned int)h1 << 16);
        unsigned int hi = (unsigned int)h2 | ((unsigned int)h3 << 16);
        ((unsigned int*)&tile[row * PAD + c4])[0] = lo;
        ((unsigned int*)&tile[row * PAD + c4])[1] = hi;
      }
      float4 nv[4];
      if (st < 3) {
#pragma unroll
        for (int r = 0; r < 4; ++r)
          nv[r] = *(const float4*)&xin[(size_t)(row16 + r * 16) * T_ + (st + 1) * 64 + c4];
      }
      __syncthreads();
#pragma unroll
      for (int r = 0; r < 2; ++r) {
        int idx = tid + r * 256;
        int trow = idx >> 3, cc = (idx & 7) << 3;
        unsigned short vals[8];
#pragma unroll
        for (int j = 0; j < 8; ++j) vals[j] = tile[(cc + j) * PAD + trow];
        *(uint4*)&XhT[((size_t)b * T_ + t0 + st * 64 + trow) * C_ + c0 + cc] =
            *(uint4*)vals;
      }
#pragma unroll
      for (int r = 0; r < 4; ++r) v[r] = nv[r];
    }
    // Fused row-sum: reduce across the 16 lanes of each row-group, one
    // atomicAdd per (row, t-block). 16 atomics/entry total -> no contention.
#pragma unroll
    for (int rr = 0; rr < 4; ++rr) {
      float s = rs[rr];
      s += __shfl_down(s, 8, 16);
      s += __shfl_down(s, 4, 16);
      s += __shfl_down(s, 2, 16);
      s += __shfl_down(s, 1, 16);
      if ((tid & 15) == 0) atomicAdd(&S[(b << 9) + c0 + row16 + rr * 16], s);
    }
  } else {
    int i = (blockIdx.x - NXB2) * 256 + tid;  // 0..C*C-1
    float q = Wq[i]; unsigned short qh = f2bf(q); Wqh[i] = qh; Wql[i] = f2bf(q - bf2f(qh));
    float k = Wk[i]; unsigned short kh = f2bf(k); Wkh[i] = kh; Wkl[i] = f2bf(k - bf2f(kh));
    float v = Wv[i]; int d = i >> 9, e = i & 511;
    WvT[(e << 9) + d] = f2h(v);
  }
}

// G combine: sum 4 splitK partials from the lower-triangle source tile
// (transposing via LDS for mirrored upper tiles) -> bf16 hi/lo full square.
__global__ __launch_bounds__(256) void combine_g(const float* __restrict__ gp,
                                                 unsigned short* __restrict__ gh,
                                                 unsigned short* __restrict__ gl) {
  __shared__ float tile[64 * 65];
  const int blk = blockIdx.x;             // b = blk&7; q = blk>>3 -> 64x64 tiles
  const int b = blk & 7, q = blk >> 3;
  const int tr = q >> 3, tc = q & 7;
  const bool mirror = (tr >> 1) < (tc >> 1);      // containing 128-tile is upper
  const int sr = mirror ? tc : tr, sc = mirror ? tr : tc;
  const float* src = gp + ((size_t)b << 20) + (size_t)(sr << 6) * 512 + (sc << 6);
  const int row = threadIdx.x >> 4, c4 = (threadIdx.x & 15) << 2;
  float vals[4][4];
#pragma unroll
  for (int rr = 0; rr < 4; ++rr) {
    const int r = row + rr * 16;
    f32x4 v = {};
#pragma unroll
    for (int p = 0; p < 4; ++p)
      v += __builtin_nontemporal_load(
          (const f32x4*)&src[((size_t)p << 18) + (size_t)r * 512 + c4]);
    if (mirror) {
#pragma unroll
      for (int k = 0; k < 4; ++k) tile[r * 65 + c4 + k] = v[k];
    } else {
#pragma unroll
      for (int k = 0; k < 4; ++k) vals[rr][k] = v[k];
    }
  }
  if (mirror) {
    __syncthreads();
#pragma unroll
    for (int rr = 0; rr < 4; ++rr) {
      const int r = row + rr * 16;
#pragma unroll
      for (int k = 0; k < 4; ++k) vals[rr][k] = tile[(c4 + k) * 65 + r];
    }
  }
  unsigned short* ghp = gh + ((size_t)b << 18) + (size_t)(tr << 6) * 512 + (tc << 6);
  unsigned short* glp = gl + ((size_t)b << 18) + (size_t)(tr << 6) * 512 + (tc << 6);
#pragma unroll
  for (int rr = 0; rr < 4; ++rr) {
    const int r = row + rr * 16;
    ushort4 h, l;
    h.x = f2bf(vals[rr][0]); l.x = f2bf(vals[rr][0] - bf2f(h.x));
    h.y = f2bf(vals[rr][1]); l.y = f2bf(vals[rr][1] - bf2f(h.y));
    h.z = f2bf(vals[rr][2]); l.z = f2bf(vals[rr][2] - bf2f(h.z));
    h.w = f2bf(vals[rr][3]); l.w = f2bf(vals[rr][3] - bf2f(h.w));
    *(ushort4*)&ghp[(size_t)r * 512 + c4] = h;
    *(ushort4*)&glp[(size_t)r * 512 + c4] = l;
  }
}

// qs[b,i] = sum_c Wq[i,c] s[b,c];  ks[b,i] = sum_c Wk[i,c] s[b,c]
__global__ __launch_bounds__(256) void qs_ks(const float* __restrict__ Wq, const float* __restrict__ Wk,
                                             const float* __restrict__ s, float* __restrict__ qs,
                                             float* __restrict__ ks) {
  int lane = threadIdx.x & 63, wid = threadIdx.x >> 6;
  int gi = blockIdx.x * 4 + wid;
  int b = gi >> 9, i = gi & 511;
  const float* sv = s + (b << 9);
  const float* wqr = Wq + (size_t)i * C_;
  const float* wkr = Wk + (size_t)i * C_;
  float aq = 0.f, ak = 0.f;
#pragma unroll
  for (int c = lane; c < C_; c += 64) {
    float sc = sv[c];
    aq += wqr[c] * sc;
    ak += wkr[c] * sc;
  }
#pragma unroll
  for (int o = 32; o > 0; o >>= 1) { aq += __shfl_down(aq, o); ak += __shfl_down(ak, o); }
  if (lane == 0) { qs[gi] = aq; ks[gi] = ak; }
}

// rowwise softmax over 512 logits; attn fp16; ab[b,c] = sum_d attn*bv[d]
__global__ __launch_bounds__(256) void softmax_rows(const float* __restrict__ logits,
                                                    const float* __restrict__ bv,
                                                    unsigned short* __restrict__ attn,
                                                    float* __restrict__ ab) {
  const int row = blockIdx.x;
  const int tid = threadIdx.x, lane = tid & 63, wid = tid >> 6;
  const float* L = logits + (size_t)row * C_;
  float v0 = __builtin_nontemporal_load(&L[tid]);
  float v1 = __builtin_nontemporal_load(&L[tid + 256]);
  __shared__ float red[4];
  float m = fmaxf(v0, v1);
#pragma unroll
  for (int o = 32; o > 0; o >>= 1) m = fmaxf(m, __shfl_down(m, o));
  if (lane == 0) red[wid] = m;
  __syncthreads();
  m = fmaxf(fmaxf(red[0], red[1]), fmaxf(red[2], red[3]));
  __syncthreads();
  float e0 = __expf(v0 - m), e1 = __expf(v1 - m);
  float sum = e0 + e1;
#pragma unroll
  for (int o = 32; o > 0; o >>= 1) sum += __shfl_down(sum, o);
  if (lane == 0) red[wid] = sum;
  __syncthreads();
  sum = red[0] + red[1] + red[2] + red[3];
  float inv = 1.f / sum;
  float a0 = e0 * inv, a1 = e1 * inv;
  unsigned short* ar = attn + (size_t)row * C_;
  ar[tid] = f2h(a0);
  ar[tid + 256] = f2h(a1);
  float abv = a0 * bv[tid] + a1 * bv[tid + 256];
  __syncthreads();
#pragma unroll
  for (int o = 32; o > 0; o >>= 1) abv += __shfl_down(abv, o);
  if (lane == 0) red[wid] = abv;
  __syncthreads();
  if (tid == 0) ab[row] = red[0] + red[1] + red[2] + red[3];
}

extern "C" void kernel_launch(void* const* d_in, const int* in_sizes, int n_in,
                              void* d_out, int out_size, void* d_ws, size_t ws_size,
                              hipStream_t stream) {
  const float* x  = (const float*)d_in[0];
  const float* Wq = (const float*)d_in[1];
  const float* bq = (const float*)d_in[2];
  const float* Wk = (const float*)d_in[3];
  const float* bk = (const float*)d_in[4];
  const float* Wv = (const float*)d_in[5];
  const float* bv = (const float*)d_in[6];
  float* out = (float*)d_out;

  char* ws = (char*)d_ws;
  size_t off = 0;
  auto alloc = [&](size_t bytes) {
    char* p = ws + off;
    off += (bytes + 255) & ~(size_t)255;
    return p;
  };
  const size_t XSZ = (size_t)B_ * C_ * T_;
  const size_t GSZ = (size_t)B_ * C_ * C_;   // 2^21

  unsigned short* Xh  = (unsigned short*)alloc(XSZ * 2);
  unsigned short* XhT = (unsigned short*)alloc(XSZ * 2);
  float* Gpart = (float*)alloc((size_t)4 * GSZ * 4);   // 33.5 MB (4 splitK parts)
  unsigned short* Gh = (unsigned short*)alloc(GSZ * 2);
  unsigned short* Gl = (unsigned short*)alloc(GSZ * 2);
  unsigned short* Ph = (unsigned short*)alloc(GSZ * 2);
  unsigned short* Pl = (unsigned short*)alloc(GSZ * 2);
  float* Logits = (float*)alloc(GSZ * 4);
  unsigned short* Attn = (unsigned short*)alloc(GSZ * 2);
  unsigned short* Mh = (unsigned short*)alloc(GSZ * 2);
  unsigned short* Wqh = (unsigned short*)alloc((size_t)C_ * C_ * 2);
  unsigned short* Wql = (unsigned short*)alloc((size_t)C_ * C_ * 2);
  unsigned short* Wkh = (unsigned short*)alloc((size_t)C_ * C_ * 2);
  unsigned short* Wkl = (unsigned short*)alloc((size_t)C_ * C_ * 2);
  unsigned short* WvT = (unsigned short*)alloc((size_t)C_ * C_ * 2);
  float* S  = (float*)alloc((size_t)B_ * C_ * 4);
  float* Qs = (float*)alloc((size_t)B_ * C_ * 4);
  float* Ks = (float*)alloc((size_t)B_ * C_ * 4);
  float* Ab = (float*)alloc((size_t)B_ * C_ * 4);

  hipMemsetAsync(S, 0, (size_t)B_ * C_ * 4, stream);
  prep_fused<<<NXB2 + C_ * C_ / 256, 256, 0, stream>>>(x, Wq, Wk, Wv, Xh, XhT,
                                                       Wqh, Wql, Wkh, Wkl, WvT, S);
  qs_ks<<<B_ * C_ / 4, 256, 0, stream>>>(Wq, Wk, S, Qs, Ks);

  {  // G = X X^T, fp16, lower-triangle 128-tiles, splitK=4, XCD-swizzled
    GemmP p = {};
    p.Ah = Xh; p.sA = (long)C_ * T_; p.lda = T_;
    p.Bh = Xh; p.sB = (long)C_ * T_; p.ldb = T_;
    p.Cf = Gpart; p.sC = (long)C_ * C_; p.ldc = C_;
    p.kspan = T_ / 4; p.zparts = 4;
    gemm_nt<128, 128, 32, 64, 64, false, false, EPI_F32, true, 1>
        <<<320, 512, 0, stream>>>(p);
  }
  combine_g<<<B_ * 64, 256, 0, stream>>>(Gpart, Gh, Gl);

  {  // P = Wq G (bf16 hi/lo 3-pass), direct split output, KC=64
    GemmP p = {};
    p.Ah = Wqh; p.Al = Wql; p.sA = 0; p.lda = C_;
    p.Bh = Gh; p.Bl = Gl; p.sB = (long)C_ * C_; p.ldb = C_;
    p.Ch = Ph; p.Cl = Pl; p.sC = (long)C_ * C_; p.ldc = C_;
    p.kspan = C_; p.zparts = 1;
    gemm_nt<64, 64, 32, 32, 64, true, true, EPI_SPLIT, false, 0>
        <<<dim3(8, 8, 8), 256, 0, stream>>>(p);
  }
  {  // logits = 0.125*(P Wk^T + rank-1 bias terms), fp32 nt stores, KC=64
    GemmP p = {};
    p.Ah = Ph; p.Al = Pl; p.sA = (long)C_ * C_; p.lda = C_;
    p.Bh = Wkh; p.Bl = Wkl; p.sB = 0; p.ldb = C_;
    p.Cf = Logits; p.sC = (long)C_ * C_; p.ldc = C_;
    p.kspan = C_; p.zparts = 1;
    p.rowv = Qs; p.colv = Ks; p.bq = bq; p.bk = bk;
    gemm_nt<64, 64, 32, 32, 64, true, true, EPI_DOTS, false, 0>
        <<<dim3(8, 8, 8), 256, 0, stream>>>(p);
  }
  softmax_rows<<<B_ * C_, 256, 0, stream>>>(Logits, bv, Attn, Ab);
  {  // M = attn Wv (fp16, NT with WvT), direct fp16 output, KC=64
    GemmP p = {};
    p.Ah = Attn; p.sA = (long)C_ * C_; p.lda = C_;
    p.Bh = WvT; p.sB = 0; p.ldb = C_;
    p.Ch = Mh; p.sC = (long)C_ * C_; p.ldc = C_;
    p.kspan = C_; p.zparts = 1;
    gemm_nt<64, 64, 32, 32, 64, false, false, EPI_F16, true, 0>
        <<<dim3(8, 8, 8), 256, 0, stream>>>(p);
  }
  {  // out = M X + ab (fp16, NT with XhT), 128x128 8-wave dbuf, KC=32
     // (32 KB LDS -> 4 blk/CU, confirmed faster R4->R5), XCD-swizzled
    GemmP p = {};
    p.Ah = Mh; p.sA = (long)C_ * C_; p.lda = C_;
    p.Bh = XhT; p.sB = (long)C_ * T_; p.ldb = C_;
    p.Cf = out; p.sC = (long)C_ * T_; p.ldc = T_;
    p.kspan = C_; p.zparts = 1;
    p.rowv = Ab;
    gemm_nt<128, 128, 32, 64, 32, false, false, EPI_OUT, true, 2>
        <<<1024, 512, 0, stream>>>(p);
  }
  (void)in_sizes; (void)n_in; (void)out_size; (void)ws_size;
}